// Round 1
// baseline (50.943 us; speedup 1.0000x reference)
//
#include <hip/hip_runtime.h>
#include <hip/hip_bf16.h>

// Analytic reduction of the reference:
//   angles = pi*tanh(MLP(x));  <Z0> = sin(theta1)*sin(theta2)  (theta0, q_params cancel)
//   out = sigmoid(5*<Z0>)
// Dominant cost: GEMM1 (65536x784 @ 784x64) -> memory-bound on reading x (205 MB).

#define BM 128
#define KDIM 784
#define BK 32
#define NITER 25      // ceil(784/32), tail zero-padded
#define ASTR 80       // LDS A row stride bytes (32 bf16 = 64B + 16B pad -> 2-way banks, free)
#define BSTR 80

using f32x4 = __attribute__((ext_vector_type(4))) float;
using s16x8 = __attribute__((ext_vector_type(8))) short;

union LdsU {
    struct { char a[BM * ASTR]; char b[64 * BSTR]; } st;  // 10240 + 5120 B
    float h1[BM * 65];                                    // 33280 B (stride 65: conflict-free col reads)
};

__device__ __forceinline__ ushort f2bf(float f) {
    uint b = __float_as_uint(f);
    b += 0x7FFFu + ((b >> 16) & 1u);   // round-to-nearest-even
    return (ushort)(b >> 16);
}
__device__ __forceinline__ uint pack2(float lo, float hi) {
    return (uint)f2bf(lo) | ((uint)f2bf(hi) << 16);
}

__global__ void hybrid_kernel(
    const float* __restrict__ x, const float* __restrict__ W1,
    const float* __restrict__ b1, const float* __restrict__ W2,
    const float* __restrict__ b2, const float* __restrict__ W3,
    const float* __restrict__ b3, float* __restrict__ out, int B)
{
    __shared__ LdsU lds;
    const int tid  = threadIdx.x;
    const int wave = tid >> 6, lane = tid & 63;
    const int row0 = blockIdx.x * BM;

    const int arow = tid >> 1, ahalf = tid & 1;   // A staging: 2 thr/row, 16 f32 each
    const int bn   = tid >> 2, bslot = tid & 3;   // B staging: 4 thr/row of W1, 8 f32 each

    f32x4 acc[2][4];
    #pragma unroll
    for (int s = 0; s < 2; ++s)
        #pragma unroll
        for (int n = 0; n < 4; ++n)
            #pragma unroll
            for (int j = 0; j < 4; ++j) acc[s][n][j] = 0.f;

    float4 aA[4], aB[2];
    float4 nA[4] = {}, nB[2] = {};

    auto loadTile = [&](int it, float4 A[4], float4 Bv[2]) {
        const int k0 = it * BK;
        const int ga = row0 + arow;
        const float* pa = x + (size_t)ga * KDIM + (k0 + ahalf * 16);
        #pragma unroll
        for (int j = 0; j < 4; ++j) {
            int kb = k0 + ahalf * 16 + j * 4;
            A[j] = (ga < B && kb < KDIM) ? *(const float4*)(pa + j * 4)
                                         : make_float4(0.f, 0.f, 0.f, 0.f);
        }
        const float* pb = W1 + (size_t)bn * KDIM + (k0 + bslot * 8);
        #pragma unroll
        for (int j = 0; j < 2; ++j) {
            int kb = k0 + bslot * 8 + j * 4;
            Bv[j] = (kb < KDIM) ? *(const float4*)(pb + j * 4)
                                : make_float4(0.f, 0.f, 0.f, 0.f);
        }
    };

    loadTile(0, aA, aB);

    for (int it = 0; it < NITER; ++it) {
        __syncthreads();   // previous tile's ds_reads complete
        {   // store staged tile (f32 regs -> bf16 LDS)
            uint4 p0 = make_uint4(pack2(aA[0].x, aA[0].y), pack2(aA[0].z, aA[0].w),
                                  pack2(aA[1].x, aA[1].y), pack2(aA[1].z, aA[1].w));
            uint4 p1 = make_uint4(pack2(aA[2].x, aA[2].y), pack2(aA[2].z, aA[2].w),
                                  pack2(aA[3].x, aA[3].y), pack2(aA[3].z, aA[3].w));
            char* dst = lds.st.a + arow * ASTR + ahalf * 32;
            *(uint4*)dst        = p0;
            *(uint4*)(dst + 16) = p1;
            uint4 pb = make_uint4(pack2(aB[0].x, aB[0].y), pack2(aB[0].z, aB[0].w),
                                  pack2(aB[1].x, aB[1].y), pack2(aB[1].z, aB[1].w));
            *(uint4*)(lds.st.b + bn * BSTR + bslot * 16) = pb;
        }
        if (it + 1 < NITER) loadTile(it + 1, nA, nB);  // prefetch overlaps MFMA phase
        __syncthreads();
        {   // fragments + 8 MFMA
            const char* abase = lds.st.a + (wave * 32 + (lane & 15)) * ASTR + (lane >> 4) * 16;
            s16x8 af0 = *(const s16x8*)abase;
            s16x8 af1 = *(const s16x8*)(abase + 16 * ASTR);
            const char* bbase = lds.st.b + (lane & 15) * BSTR + (lane >> 4) * 16;
            #pragma unroll
            for (int n = 0; n < 4; ++n) {
                s16x8 bfr = *(const s16x8*)(bbase + n * 16 * BSTR);
                acc[0][n] = __builtin_amdgcn_mfma_f32_16x16x32_bf16(af0, bfr, acc[0][n], 0, 0, 0);
                acc[1][n] = __builtin_amdgcn_mfma_f32_16x16x32_bf16(af1, bfr, acc[1][n], 0, 0, 0);
            }
        }
        #pragma unroll
        for (int j = 0; j < 4; ++j) aA[j] = nA[j];
        aB[0] = nB[0]; aB[1] = nB[1];
    }

    __syncthreads();   // staging LDS dead; reuse as h1
    // epilogue: h1 = relu(acc + b1); C layout: col=lane&15, row=(lane>>4)*4+reg (m89)
    #pragma unroll
    for (int s = 0; s < 2; ++s) {
        #pragma unroll
        for (int n = 0; n < 4; ++n) {
            int c = n * 16 + (lane & 15);
            float bias = b1[c];
            #pragma unroll
            for (int j = 0; j < 4; ++j) {
                int r = wave * 32 + s * 16 + (lane >> 4) * 4 + j;
                lds.h1[r * 65 + c] = fmaxf(acc[s][n][j] + bias, 0.f);
            }
        }
    }
    __syncthreads();

    if (tid < BM) {
        int grow = row0 + tid;
        if (grow < B) {
            const float* h1p = &lds.h1[tid * 65];
            float h2[16];
            #pragma unroll
            for (int j2 = 0; j2 < 16; ++j2) {
                float s = b2[j2];
                #pragma unroll
                for (int k = 0; k < 64; ++k) s = fmaf(h1p[k], W2[j2 * 64 + k], s);
                h2[j2] = fmaxf(s, 0.f);
            }
            float a1 = b3[1], a2 = b3[2];
            #pragma unroll
            for (int j2 = 0; j2 < 16; ++j2) {
                a1 = fmaf(h2[j2], W3[16 + j2], a1);
                a2 = fmaf(h2[j2], W3[32 + j2], a2);
            }
            // theta = pi*tanh(a); tanh via exp (accurate to ~1e-6)
            float t1 = 1.f - 2.f / (__expf(2.f * a1) + 1.f);
            float t2 = 1.f - 2.f / (__expf(2.f * a2) + 1.f);
            const float PI = 3.14159265358979323846f;
            float z0 = __sinf(PI * t1) * __sinf(PI * t2);
            out[grow] = 1.f / (1.f + __expf(-5.f * z0));
        }
    }
}

extern "C" void kernel_launch(void* const* d_in, const int* in_sizes, int n_in,
                              void* d_out, int out_size, void* d_ws, size_t ws_size,
                              hipStream_t stream) {
    const float* x  = (const float*)d_in[0];
    const float* W1 = (const float*)d_in[1];
    const float* b1 = (const float*)d_in[2];
    const float* W2 = (const float*)d_in[3];
    const float* b2 = (const float*)d_in[4];
    const float* W3 = (const float*)d_in[5];
    const float* b3 = (const float*)d_in[6];
    // d_in[7] = q_params: unused (RZ phases cancel in |psi|^2)
    int B = in_sizes[0] / KDIM;
    int grid = (B + BM - 1) / BM;
    hybrid_kernel<<<grid, 256, 0, stream>>>(x, W1, b1, W2, b2, W3, b3, (float*)d_out, B);
}